// Round 2
// baseline (163.144 us; speedup 1.0000x reference)
//
#include <hip/hip_runtime.h>
#include <hip/hip_bf16.h>
#include <cstdint>

// Problem constants
#define NPTS  131072
#define NRET  65536
#define NBAT  64
#define NBUCK (1 << 18)   // buckets = top-18 bits of descending key
#define BSH   14          // d >> 14 -> bucket

// Monotone map f32 -> u32 such that ascending u32 == DESCENDING float value.
__device__ __forceinline__ unsigned int desc_key(float w) {
    unsigned int b = __float_as_uint(w);
    unsigned int s = b ^ ((unsigned int)((int)b >> 31) | 0x80000000u); // ascending
    return ~s;                                                        // descending
}

// ---------- max reduction (exact, order-independent) ----------
__global__ void k_pmax(const float* __restrict__ w, float* __restrict__ pmax) {
    __shared__ float sm[256];
    int tid = threadIdx.x;
    float m = -3.402823466e38f;
    for (int i = blockIdx.x * 256 + tid; i < NPTS; i += gridDim.x * 256)
        m = fmaxf(m, w[i]);
    sm[tid] = m; __syncthreads();
    for (int off = 128; off > 0; off >>= 1) {
        if (tid < off) sm[tid] = fmaxf(sm[tid], sm[tid + off]);
        __syncthreads();
    }
    if (tid == 0) pmax[blockIdx.x] = sm[0];
}

__global__ void k_fmax(const float* __restrict__ pmax, float* __restrict__ scal) {
    __shared__ float sm[256];
    int tid = threadIdx.x;
    sm[tid] = pmax[tid]; __syncthreads();
    for (int off = 128; off > 0; off >>= 1) {
        if (tid < off) sm[tid] = fmaxf(sm[tid], sm[tid + off]);
        __syncthreads();
    }
    if (tid == 0) scal[0] = sm[0];
}

// e_i = correctly-rounded f32 exp(f32(w_i - m)) via double
__global__ void k_exp(const float* __restrict__ w, const float* __restrict__ scal,
                      float* __restrict__ e_out) {
    int i = blockIdx.x * 256 + threadIdx.x;
    float t = w[i] - scal[0];          // f32 subtract, matches np
    e_out[i] = (float)exp((double)t);  // round-to-nearest f32 of true exp
}

// ---------- numpy pairwise-sum replica ----------
// Base: 128-element blocks, 8 interleaved accumulators, numpy's combine order.
__global__ void k_base128(const float* __restrict__ a, float* __restrict__ bs) {
    int t = blockIdx.x * 256 + threadIdx.x;       // 0..1023
    const float* p = a + (size_t)t * 128;
    float r0=p[0],r1=p[1],r2=p[2],r3=p[3],r4=p[4],r5=p[5],r6=p[6],r7=p[7];
    for (int i = 8; i < 128; i += 8) {
        r0+=p[i+0]; r1+=p[i+1]; r2+=p[i+2]; r3+=p[i+3];
        r4+=p[i+4]; r5+=p[i+5]; r6+=p[i+6]; r7+=p[i+7];
    }
    bs[t] = ((r0+r1)+(r2+r3))+((r4+r5)+(r6+r7));
}

// Perfect binary combine tree over 1024 base sums (numpy's recursion shape).
// mode 0: dst = sum ; mode 1: dst = 1/(sum + 1e-6)
__global__ void k_tree(const float* __restrict__ bs, float* __restrict__ dst, int mode) {
    __shared__ float sm[1024];
    int tid = threadIdx.x;
    sm[tid] = bs[tid]; __syncthreads();
    for (int n = 512; n >= 1; n >>= 1) {
        float v = 0.0f;
        if (tid < n) v = sm[2*tid] + sm[2*tid+1];
        __syncthreads();
        if (tid < n) sm[tid] = v;
        __syncthreads();
    }
    if (tid == 0) dst[0] = mode ? (1.0f / (sm[0] + 1e-6f)) : sm[0];
}

// p_i = e_i / Z (IEEE f32 div, matches np given same e,Z bits); histogram buckets.
__global__ void k_prob_hist(float* __restrict__ probs, const float* __restrict__ scal,
                            unsigned int* __restrict__ hist) {
    int i = blockIdx.x * 256 + threadIdx.x;
    float pv = probs[i] / scal[1];
    probs[i] = pv;
    atomicAdd(&hist[desc_key(pv) >> BSH], 1u);
}

// ---------- bucket ranking sort ----------
__global__ void k_scan_local(const unsigned int* __restrict__ hist,
                             unsigned int* __restrict__ local,
                             unsigned int* __restrict__ chunksum) {
    __shared__ unsigned int sm[1024];
    int tid = threadIdx.x;
    int g = blockIdx.x * 1024 + tid;
    unsigned int v = hist[g];
    sm[tid] = v; __syncthreads();
    for (int off = 1; off < 1024; off <<= 1) {
        unsigned int t = (tid >= off) ? sm[tid - off] : 0u;
        __syncthreads();
        sm[tid] += t;
        __syncthreads();
    }
    local[g] = sm[tid] - v;                  // exclusive within chunk
    if (tid == 1023) chunksum[blockIdx.x] = sm[1023];
}

__global__ void k_scan_chunk(const unsigned int* __restrict__ chunksum,
                             unsigned int* __restrict__ chunkoff) {
    __shared__ unsigned int sm[256];
    int tid = threadIdx.x;
    unsigned int v = chunksum[tid];
    sm[tid] = v; __syncthreads();
    for (int off = 1; off < 256; off <<= 1) {
        unsigned int t = (tid >= off) ? sm[tid - off] : 0u;
        __syncthreads();
        sm[tid] += t;
        __syncthreads();
    }
    chunkoff[tid] = sm[tid] - v;
}

// Scatter unique key (desc_prob_bits<<17)|idx into its bucket segment.
__global__ void k_scatter(const float* __restrict__ probs,
                          const unsigned int* __restrict__ local,
                          const unsigned int* __restrict__ chunkoff,
                          unsigned int* __restrict__ cnt,
                          unsigned long long* __restrict__ bucketed) {
    int i = blockIdx.x * 256 + threadIdx.x;
    unsigned int d = desc_key(probs[i]);
    unsigned int b = d >> BSH;
    unsigned int base = chunkoff[b >> 10] + local[b];
    unsigned int off = atomicAdd(&cnt[b], 1u);
    bucketed[base + off] = ((unsigned long long)d << 17) | (unsigned int)i;
}

// Exact global rank = bucket base + (# strictly smaller keys in bucket).
// Keys unique -> permutation -> deterministic. Equal probs order index-asc.
__global__ void k_rank(const unsigned long long* __restrict__ bucketed,
                       const unsigned int* __restrict__ hist,
                       const unsigned int* __restrict__ local,
                       const unsigned int* __restrict__ chunkoff,
                       unsigned int* __restrict__ ret_idx) {
    int p = blockIdx.x * 256 + threadIdx.x;
    unsigned long long kk = bucketed[p];
    unsigned int b = (unsigned int)(kk >> 31);        // (d<<17)>>31 == d>>14
    unsigned int start = chunkoff[b >> 10] + local[b];
    unsigned int len = hist[b];
    unsigned int c = 0;
    for (unsigned int q = start; q < start + len; ++q)
        c += (bucketed[q] < kk) ? 1u : 0u;
    unsigned int rank = start + c;
    if (rank < NRET) ret_idx[rank] = (unsigned int)(kk & 0x1FFFFu);
}

// ---------- final gather ----------
__global__ void k_gather(const float4* __restrict__ pts,
                         const unsigned int* __restrict__ ret_idx,
                         const float* __restrict__ probs,
                         const float* __restrict__ scal,
                         float4* __restrict__ out) {
    int t = blockIdx.x * 256 + threadIdx.x;   // [0, NBAT*NRET)
    int r = t & (NRET - 1);
    int bb = t >> 16;                          // NRET == 2^16
    unsigned int i = ret_idx[r];
    float s = probs[i] * scal[2];
    float4 v = pts[(size_t)bb * NPTS + i];
    v.x *= s; v.y *= s; v.z *= s; v.w *= s;
    out[t] = v;
}

extern "C" void kernel_launch(void* const* d_in, const int* in_sizes, int n_in,
                              void* d_out, int out_size, void* d_ws, size_t ws_size,
                              hipStream_t stream) {
    const float* pts = (const float*)d_in[0];   // [64, 131072, 4]
    const float* w   = (const float*)d_in[1];   // [131072]
    float* out = (float*)d_out;

    char* ws = (char*)d_ws;
    unsigned int* hist      = (unsigned int*)(ws + 0);                 // 1 MB
    unsigned int* cnt       = (unsigned int*)(ws + (1 << 20));         // 1 MB
    unsigned int* local     = (unsigned int*)(ws + (2 << 20));         // 1 MB
    unsigned int* chunksum  = (unsigned int*)(ws + (3 << 20));         // 1 KB
    unsigned int* chunkoff  = (unsigned int*)(ws + (3 << 20) + 4096);  // 1 KB
    float*        pmax      = (float*)(ws + (3 << 20) + 8192);         // 1 KB
    float*        scal      = (float*)(ws + (3 << 20) + 12288);        // m, Z, inv
    float*        bs        = (float*)(ws + (3 << 20) + 16384);        // 4 KB
    float*        bs2       = (float*)(ws + (3 << 20) + 24576);        // 4 KB
    float*        probs     = (float*)(ws + (3 << 20) + (1 << 19));    // 512 KB
    unsigned long long* bucketed = (unsigned long long*)(ws + (4 << 20)); // 1 MB
    unsigned int* ret_idx   = (unsigned int*)(ws + (5 << 20));         // 256 KB

    hipMemsetAsync(ws, 0, 2 << 20, stream);    // zero hist + cnt

    k_pmax      <<<256, 256, 0, stream>>>(w, pmax);
    k_fmax      <<<1,   256, 0, stream>>>(pmax, scal);
    k_exp       <<<NPTS / 256, 256, 0, stream>>>(w, scal, probs);   // probs = e
    k_base128   <<<4,   256, 0, stream>>>(probs, bs);
    k_tree      <<<1,  1024, 0, stream>>>(bs, &scal[1], 0);         // Z
    k_prob_hist <<<NPTS / 256, 256, 0, stream>>>(probs, scal, hist); // probs = p
    k_base128   <<<4,   256, 0, stream>>>(probs, bs2);
    k_tree      <<<1,  1024, 0, stream>>>(bs2, &scal[2], 1);        // 1/(S+1e-6)
    k_scan_local<<<NBUCK / 1024, 1024, 0, stream>>>(hist, local, chunksum);
    k_scan_chunk<<<1,   256, 0, stream>>>(chunksum, chunkoff);
    k_scatter   <<<NPTS / 256, 256, 0, stream>>>(probs, local, chunkoff, cnt, bucketed);
    k_rank      <<<NPTS / 256, 256, 0, stream>>>(bucketed, hist, local, chunkoff, ret_idx);
    k_gather    <<<(NBAT * NRET) / 256, 256, 0, stream>>>(
        (const float4*)pts, ret_idx, probs, scal, (float4*)out);
}